// Round 1
// baseline (2830.798 us; speedup 1.0000x reference)
//
#include <hip/hip_runtime.h>

#define VOCAB 32000
#define EMB 512
#define HID 512
#define NTAG 36
#define SEQ 512
#define G4H 2048   // 4*HID
#define NBLK 128
#define XCHUNK 32

typedef unsigned long long ull;

__device__ __forceinline__ float fast_tanh(float x) {
    // 1 - 2/(e^{2x}+1); saturates to +-1 correctly for large |x|
    float e = __expf(2.f * x);
    return 1.f - 2.f / (e + 1.f);
}
__device__ __forceinline__ float fast_sigmoid(float x) {
    return 1.f / (1.f + __expf(-x));
}

// ---------------------------------------------------------------------------
// Kernel A: Z[t][r] = W_ih[tag_t] @ emb[x_t] + b_ih[tag_t] + b_hh[tag_t]
// grid (NTAG, 32): block = (tag, 64-row chunk). 4-row batching per wave;
// W_ih read ~once. (unchanged — lstm_seq still dominates)
// ---------------------------------------------------------------------------
__global__ __launch_bounds__(256) void precompute_z(
    const int* __restrict__ x,          // [SEQ] token ids
    const int* __restrict__ tag_ids,    // [SEQ]
    const float* __restrict__ emb,      // [VOCAB, EMB]
    const float* __restrict__ W_ih,     // [NTAG, G4H, EMB]
    const float* __restrict__ b_ih,     // [NTAG, G4H]
    const float* __restrict__ b_hh,     // [NTAG, G4H]
    float* __restrict__ Z)              // [SEQ, G4H]
{
    __shared__ int list[SEQ];
    __shared__ int cnt;
    __shared__ __align__(16) float xc[XCHUNK][EMB];   // 64 KB x-cache

    const int tid  = threadIdx.x;
    const int tag  = blockIdx.x;
    const int row0 = blockIdx.y * 64;
    const int wave = tid >> 6, lane = tid & 63;

    if (tid == 0) cnt = 0;
    __syncthreads();
    for (int t = tid; t < SEQ; t += 256)
        if (tag_ids[t] == tag) { int p = atomicAdd(&cnt, 1); list[p] = t; }
    __syncthreads();
    const int n = cnt;

    for (int c0 = 0; c0 < n; c0 += XCHUNK) {
        const int nc = min(XCHUNK, n - c0);
        __syncthreads();   // protect xc before overwrite
        for (int idx = tid; idx < nc * 128; idx += 256) {
            int tl = idx >> 7, k4 = idx & 127;
            int t = list[c0 + tl];
            ((float4*)xc[tl])[k4] = ((const float4*)(emb + (size_t)x[t] * EMB))[k4];
        }
        __syncthreads();
        for (int rr = 0; rr < 16; rr += 4) {
            const int row = row0 + wave * 16 + rr;
            const float* w0p = W_ih + ((size_t)tag * G4H + row) * EMB;
            const float* w1p = w0p + EMB;
            const float* w2p = w0p + 2 * EMB;
            const float* w3p = w0p + 3 * EMB;
            const float4 wa0 = ((const float4*)w0p)[lane], wa1 = ((const float4*)w0p)[64 + lane];
            const float4 wb0 = ((const float4*)w1p)[lane], wb1 = ((const float4*)w1p)[64 + lane];
            const float4 wc0 = ((const float4*)w2p)[lane], wc1 = ((const float4*)w2p)[64 + lane];
            const float4 wd0 = ((const float4*)w3p)[lane], wd1 = ((const float4*)w3p)[64 + lane];
            const float bi0 = b_ih[tag * G4H + row]     + b_hh[tag * G4H + row];
            const float bi1 = b_ih[tag * G4H + row + 1] + b_hh[tag * G4H + row + 1];
            const float bi2 = b_ih[tag * G4H + row + 2] + b_hh[tag * G4H + row + 2];
            const float bi3 = b_ih[tag * G4H + row + 3] + b_hh[tag * G4H + row + 3];
            for (int tl = 0; tl < nc; ++tl) {
                float4 x0 = *(const float4*)&xc[tl][4 * lane];
                float4 x1 = *(const float4*)&xc[tl][256 + 4 * lane];
                float d0 = wa0.x*x0.x + wa0.y*x0.y + wa0.z*x0.z + wa0.w*x0.w
                         + wa1.x*x1.x + wa1.y*x1.y + wa1.z*x1.z + wa1.w*x1.w;
                float d1 = wb0.x*x0.x + wb0.y*x0.y + wb0.z*x0.z + wb0.w*x0.w
                         + wb1.x*x1.x + wb1.y*x1.y + wb1.z*x1.z + wb1.w*x1.w;
                float d2 = wc0.x*x0.x + wc0.y*x0.y + wc0.z*x0.z + wc0.w*x0.w
                         + wc1.x*x1.x + wc1.y*x1.y + wc1.z*x1.z + wc1.w*x1.w;
                float d3 = wd0.x*x0.x + wd0.y*x0.y + wd0.z*x0.z + wd0.w*x0.w
                         + wd1.x*x1.x + wd1.y*x1.y + wd1.z*x1.z + wd1.w*x1.w;
                #pragma unroll
                for (int m = 32; m >= 1; m >>= 1) {
                    d0 += __shfl_xor(d0, m, 64);
                    d1 += __shfl_xor(d1, m, 64);
                    d2 += __shfl_xor(d2, m, 64);
                    d3 += __shfl_xor(d3, m, 64);
                }
                if (lane == 0) {
                    float* zr = Z + (size_t)list[c0 + tl] * G4H + row;
                    zr[0] = d0 + bi0; zr[1] = d1 + bi1;
                    zr[2] = d2 + bi2; zr[3] = d3 + bi3;
                }
            }
        }
    }
}

// ---------------------------------------------------------------------------
// Kernel B: sequential LSTM. 128 co-resident blocks; block b, wave w owns
// h index j = 4b + w. Handshake: packed {f32 h, u32 step+1} relaxed agent
// atomics into hist. R5: depth-4 pipelined poll.
// R6 (this round): register double-buffered W_hh/Z prefetch one step ahead,
// issued right after the poll succeeds; per-step __syncthreads replaced by
// s_waitcnt lgkmcnt(0) + raw s_barrier so the in-flight vmem prefetch is NOT
// drained at the barrier (hipcc's __syncthreads emits vmcnt(0)). The 4 MB/step
// W_hh drain now overlaps the h-handshake instead of serializing with it.
// LDS h-broadcast stays double-buffered (hsh[t&1]); each wave's ds_reads are
// lgkm-drained before its next barrier arrival, so parity writes can't race.
// No memset: 0xAA poison never matches a valid tag (1..512).
// ---------------------------------------------------------------------------
__global__ __launch_bounds__(256) void lstm_seq(
    const int* __restrict__ tag_ids,
    const float* __restrict__ h0,       // [HID]
    const float* __restrict__ c0,       // [HID]
    const float* __restrict__ W_hh,     // [NTAG, G4H, HID]
    const float* __restrict__ Z,        // [SEQ, G4H]
    const float* __restrict__ W_fc,     // [HID]
    const float* __restrict__ b_fc,     // [1]
    ull* __restrict__ hist,             // [SEQ, HID] packed {tag,f32} scratch
    float* __restrict__ d_out)          // [1 + HID + HID]
{
    __shared__ int tags[SEQ];
    __shared__ __align__(16) float hsh[2][HID];
    __shared__ float red[256];

    const int tid  = threadIdx.x;
    const int b    = blockIdx.x;
    const int wave = tid >> 6, lane = tid & 63;
    const int j    = b * 4 + wave;      // owned h index

    for (int t = tid; t < SEQ; t += 256) tags[t] = tag_ids[t];
    __syncthreads();

    float c    = (lane == 0) ? c0[j] : 0.f;
    float hval = 0.f;

    // double-buffered weight fragments (8 float4 = 32 VGPR each buffer)
    float4 A0, A1, A2, A3, A4, A5, A6, A7;
    float4 B0, B1, B2, B3, B4, B5, B6, B7;
    float  Azi = 0.f, Azf = 0.f, Azg = 0.f, Azo = 0.f;
    float  Bzi = 0.f, Bzf = 0.f, Bzg = 0.f, Bzo = 0.f;

// Issue the h-independent loads for step T. Trailing empty-asm memory fence
// pins issuance here (loads may not sink toward their use in the next step).
#define ISSUE(T, W0,W1,W2,W3,W4,W5,W6,W7, ZI,ZF,ZG,ZO)                       \
    do {                                                                      \
        const int tg_ = tags[(T)];                                            \
        const float* wb_ = W_hh + (size_t)tg_ * (size_t)G4H * HID;            \
        const float4* r_;                                                     \
        r_ = (const float4*)(wb_ + (size_t)(j)        * HID);                 \
        W0 = r_[lane];  W1 = r_[64 + lane];                                   \
        r_ = (const float4*)(wb_ + (size_t)(512 + j)  * HID);                 \
        W2 = r_[lane];  W3 = r_[64 + lane];                                   \
        r_ = (const float4*)(wb_ + (size_t)(1024 + j) * HID);                 \
        W4 = r_[lane];  W5 = r_[64 + lane];                                   \
        r_ = (const float4*)(wb_ + (size_t)(1536 + j) * HID);                 \
        W6 = r_[lane];  W7 = r_[64 + lane];                                   \
        if (lane == 0) {                                                      \
            const float* zt_ = Z + (size_t)(T) * G4H;                         \
            ZI = zt_[j];        ZF = zt_[512 + j];                            \
            ZG = zt_[1024 + j]; ZO = zt_[1536 + j];                           \
        }                                                                     \
        asm volatile("" ::: "memory");                                        \
    } while (0)

// One LSTM step consuming weight buffer W*, prefetching into N*.
// Order: poll h[t-1] -> issue t+1 loads (max head start before the next
// step's poll FIFO-forces them) -> LDS broadcast -> lgkm-only barrier ->
// dots -> reduce -> lane0 gates + store.
#define STEP(T, W0,W1,W2,W3,W4,W5,W6,W7, ZI,ZF,ZG,ZO,                         \
                N0,N1,N2,N3,N4,N5,N6,N7, NZI,NZF,NZG,NZO)                     \
    do {                                                                      \
        const int t_ = (T);                                                   \
        float v0_, v1_;                                                       \
        if (t_ == 0) {                                                        \
            v0_ = h0[2 * tid]; v1_ = h0[2 * tid + 1];                         \
        } else {                                                              \
            const ull* pa_ = hist + (size_t)(t_ - 1) * HID + 2 * tid;         \
            const ull* pb_ = pa_ + 1;                                         \
            const unsigned want_ = (unsigned)t_;                              \
            /* depth-4 pipelined poll: examine oldest sample while 3 newer */ \
            /* are in flight -> sampling period ~ latency/3.              */  \
            ull a0_ = __hip_atomic_load(pa_, __ATOMIC_RELAXED, __HIP_MEMORY_SCOPE_AGENT); \
            ull b0_ = __hip_atomic_load(pb_, __ATOMIC_RELAXED, __HIP_MEMORY_SCOPE_AGENT); \
            ull a1_ = __hip_atomic_load(pa_, __ATOMIC_RELAXED, __HIP_MEMORY_SCOPE_AGENT); \
            ull b1_ = __hip_atomic_load(pb_, __ATOMIC_RELAXED, __HIP_MEMORY_SCOPE_AGENT); \
            ull a2_ = __hip_atomic_load(pa_, __ATOMIC_RELAXED, __HIP_MEMORY_SCOPE_AGENT); \
            ull b2_ = __hip_atomic_load(pb_, __ATOMIC_RELAXED, __HIP_MEMORY_SCOPE_AGENT); \
            while ((unsigned)(a0_ >> 32) != want_ ||                          \
                   (unsigned)(b0_ >> 32) != want_) {                          \
                a0_ = a1_; b0_ = b1_;                                         \
                a1_ = a2_; b1_ = b2_;                                         \
                a2_ = __hip_atomic_load(pa_, __ATOMIC_RELAXED, __HIP_MEMORY_SCOPE_AGENT); \
                b2_ = __hip_atomic_load(pb_, __ATOMIC_RELAXED, __HIP_MEMORY_SCOPE_AGENT); \
            }                                                                 \
            v0_ = __uint_as_float((unsigned)a0_);                             \
            v1_ = __uint_as_float((unsigned)b0_);                             \
        }                                                                     \
        /* prefetch NEXT step's weights/Z: overlaps broadcast+dots+gates   */ \
        /* of this step and the whole next handshake.                      */ \
        if (t_ + 1 < SEQ)                                                     \
            ISSUE(t_ + 1, N0,N1,N2,N3,N4,N5,N6,N7, NZI,NZF,NZG,NZO);          \
        const int hb_ = t_ & 1;                                               \
        hsh[hb_][2 * tid]     = v0_;                                          \
        hsh[hb_][2 * tid + 1] = v1_;                                          \
        /* lgkm-only barrier: do NOT drain vmcnt (prefetch stays in flight) */\
        asm volatile("s_waitcnt lgkmcnt(0)" ::: "memory");                    \
        __builtin_amdgcn_s_barrier();                                         \
        __builtin_amdgcn_sched_barrier(0);                                    \
        const float4 ha_ = *(const float4*)&hsh[hb_][4 * lane];               \
        const float4 hc_ = *(const float4*)&hsh[hb_][256 + 4 * lane];         \
        float di_  = W0.x*ha_.x + W0.y*ha_.y + W0.z*ha_.z + W0.w*ha_.w        \
                   + W1.x*hc_.x + W1.y*hc_.y + W1.z*hc_.z + W1.w*hc_.w;       \
        float df_  = W2.x*ha_.x + W2.y*ha_.y + W2.z*ha_.z + W2.w*ha_.w        \
                   + W3.x*hc_.x + W3.y*hc_.y + W3.z*hc_.z + W3.w*hc_.w;       \
        float dg_  = W4.x*ha_.x + W4.y*ha_.y + W4.z*ha_.z + W4.w*ha_.w        \
                   + W5.x*hc_.x + W5.y*hc_.y + W5.z*hc_.z + W5.w*hc_.w;       \
        float do2_ = W6.x*ha_.x + W6.y*ha_.y + W6.z*ha_.z + W6.w*ha_.w        \
                   + W7.x*hc_.x + W7.y*hc_.y + W7.z*hc_.z + W7.w*hc_.w;       \
        _Pragma("unroll")                                                     \
        for (int m_ = 32; m_ >= 1; m_ >>= 1) {                                \
            di_  += __shfl_xor(di_,  m_, 64);                                 \
            df_  += __shfl_xor(df_,  m_, 64);                                 \
            dg_  += __shfl_xor(dg_,  m_, 64);                                 \
            do2_ += __shfl_xor(do2_, m_, 64);                                 \
        }                                                                     \
        if (lane == 0) {                                                      \
            float gi_ = ZI + di_,  gf_ = ZF + df_;                            \
            float gg_ = ZG + dg_,  go_ = ZO + do2_;                           \
            float si_  = fast_sigmoid(gi_);                                   \
            float sf_  = fast_sigmoid(gf_);                                   \
            float so_  = fast_sigmoid(go_);                                   \
            float tg2_ = fast_tanh(gg_);                                      \
            c = sf_ * c + si_ * tg2_;                                         \
            hval = so_ * fast_tanh(c);                                        \
            ull pk_ = ((ull)(unsigned)(t_ + 1) << 32)                         \
                    | (ull)__float_as_uint(hval);                             \
            __hip_atomic_store(&hist[(size_t)t_ * HID + j], pk_,              \
                               __ATOMIC_RELAXED, __HIP_MEMORY_SCOPE_AGENT);   \
        }                                                                     \
    } while (0)

    // prologue: weights/Z for step 0 into buffer A
    ISSUE(0, A0,A1,A2,A3,A4,A5,A6,A7, Azi,Azf,Azg,Azo);

    for (int t = 0; t < SEQ; t += 2) {
        STEP(t,     A0,A1,A2,A3,A4,A5,A6,A7, Azi,Azf,Azg,Azo,
                    B0,B1,B2,B3,B4,B5,B6,B7, Bzi,Bzf,Bzg,Bzo);
        STEP(t + 1, B0,B1,B2,B3,B4,B5,B6,B7, Bzi,Bzf,Bzg,Bzo,
                    A0,A1,A2,A3,A4,A5,A6,A7, Azi,Azf,Azg,Azo);
    }
#undef STEP
#undef ISSUE

    // ---- epilogue: h, c slices ----
    if (lane == 0) {
        d_out[1 + j]       = hval;
        d_out[1 + HID + j] = c;
    }

    // ---- block 0: out = sigmoid(h_final . W_fc + b_fc) ----
    if (b == 0) {
        const ull* hp = hist + (size_t)(SEQ - 1) * HID;
        ull a  = __hip_atomic_load(&hp[2 * tid],     __ATOMIC_RELAXED, __HIP_MEMORY_SCOPE_AGENT);
        ull bq = __hip_atomic_load(&hp[2 * tid + 1], __ATOMIC_RELAXED, __HIP_MEMORY_SCOPE_AGENT);
        while ((unsigned)(a >> 32) != (unsigned)SEQ || (unsigned)(bq >> 32) != (unsigned)SEQ) {
            a  = __hip_atomic_load(&hp[2 * tid],     __ATOMIC_RELAXED, __HIP_MEMORY_SCOPE_AGENT);
            bq = __hip_atomic_load(&hp[2 * tid + 1], __ATOMIC_RELAXED, __HIP_MEMORY_SCOPE_AGENT);
        }
        float s = __uint_as_float((unsigned)a)  * W_fc[2 * tid]
                + __uint_as_float((unsigned)bq) * W_fc[2 * tid + 1];
        red[tid] = s;
        __syncthreads();
        #pragma unroll
        for (int off = 128; off > 0; off >>= 1) {
            if (tid < off) red[tid] += red[tid + off];
            __syncthreads();
        }
        if (tid == 0)
            d_out[0] = fast_sigmoid(red[0] + b_fc[0]);
    }
}

extern "C" void kernel_launch(void* const* d_in, const int* in_sizes, int n_in,
                              void* d_out, int out_size, void* d_ws, size_t ws_size,
                              hipStream_t stream) {
    const int*   x       = (const int*)d_in[0];
    const int*   tag_ids = (const int*)d_in[1];
    const float* h0      = (const float*)d_in[2];
    const float* c0      = (const float*)d_in[3];
    const float* emb     = (const float*)d_in[4];
    const float* W_ih    = (const float*)d_in[5];
    const float* W_hh    = (const float*)d_in[6];
    const float* b_ih    = (const float*)d_in[7];
    const float* b_hh    = (const float*)d_in[8];
    const float* W_fc    = (const float*)d_in[9];
    const float* b_fc    = (const float*)d_in[10];
    float* out = (float*)d_out;

    // workspace layout: Z (4 MB) | hist (2 MB). No memset: 0xAA poison never
    // matches a valid step tag (1..512).
    const size_t zBytes = (size_t)SEQ * G4H * sizeof(float);
    float* Z    = (float*)d_ws;
    ull*   hist = (ull*)((char*)d_ws + zBytes);

    dim3 gA(NTAG, 32);
    precompute_z<<<gA, 256, 0, stream>>>(x, tag_ids, emb, W_ih, b_ih, b_hh, Z);
    lstm_seq<<<NBLK, 256, 0, stream>>>(tag_ids, h0, c0, W_hh, Z, W_fc, b_fc,
                                       hist, out);
}

// Round 2
// 1514.219 us; speedup vs baseline: 1.8695x; 1.8695x over previous
//
#include <hip/hip_runtime.h>

#define VOCAB 32000
#define EMB 512
#define HID 512
#define NTAG 36
#define SEQ 512
#define G4H 2048   // 4*HID
#define NBLK 128
#define XCHUNK 32

typedef unsigned long long ull;

__device__ __forceinline__ float fast_tanh(float x) {
    // 1 - 2/(e^{2x}+1); saturates to +-1 correctly for large |x|
    float e = __expf(2.f * x);
    return 1.f - 2.f / (e + 1.f);
}
__device__ __forceinline__ float fast_sigmoid(float x) {
    return 1.f / (1.f + __expf(-x));
}

// ---------------------------------------------------------------------------
// Kernel A: Z[t][r] = W_ih[tag_t] @ emb[x_t] + b_ih[tag_t] + b_hh[tag_t]
// grid (NTAG, 32): block = (tag, 64-row chunk). 4-row batching per wave;
// W_ih read ~once. (unchanged — lstm_seq still dominates)
// ---------------------------------------------------------------------------
__global__ __launch_bounds__(256) void precompute_z(
    const int* __restrict__ x,          // [SEQ] token ids
    const int* __restrict__ tag_ids,    // [SEQ]
    const float* __restrict__ emb,      // [VOCAB, EMB]
    const float* __restrict__ W_ih,     // [NTAG, G4H, EMB]
    const float* __restrict__ b_ih,     // [NTAG, G4H]
    const float* __restrict__ b_hh,     // [NTAG, G4H]
    float* __restrict__ Z)              // [SEQ, G4H]
{
    __shared__ int list[SEQ];
    __shared__ int cnt;
    __shared__ __align__(16) float xc[XCHUNK][EMB];   // 64 KB x-cache

    const int tid  = threadIdx.x;
    const int tag  = blockIdx.x;
    const int row0 = blockIdx.y * 64;
    const int wave = tid >> 6, lane = tid & 63;

    if (tid == 0) cnt = 0;
    __syncthreads();
    for (int t = tid; t < SEQ; t += 256)
        if (tag_ids[t] == tag) { int p = atomicAdd(&cnt, 1); list[p] = t; }
    __syncthreads();
    const int n = cnt;

    for (int c0 = 0; c0 < n; c0 += XCHUNK) {
        const int nc = min(XCHUNK, n - c0);
        __syncthreads();   // protect xc before overwrite
        for (int idx = tid; idx < nc * 128; idx += 256) {
            int tl = idx >> 7, k4 = idx & 127;
            int t = list[c0 + tl];
            ((float4*)xc[tl])[k4] = ((const float4*)(emb + (size_t)x[t] * EMB))[k4];
        }
        __syncthreads();
        for (int rr = 0; rr < 16; rr += 4) {
            const int row = row0 + wave * 16 + rr;
            const float* w0p = W_ih + ((size_t)tag * G4H + row) * EMB;
            const float* w1p = w0p + EMB;
            const float* w2p = w0p + 2 * EMB;
            const float* w3p = w0p + 3 * EMB;
            const float4 wa0 = ((const float4*)w0p)[lane], wa1 = ((const float4*)w0p)[64 + lane];
            const float4 wb0 = ((const float4*)w1p)[lane], wb1 = ((const float4*)w1p)[64 + lane];
            const float4 wc0 = ((const float4*)w2p)[lane], wc1 = ((const float4*)w2p)[64 + lane];
            const float4 wd0 = ((const float4*)w3p)[lane], wd1 = ((const float4*)w3p)[64 + lane];
            const float bi0 = b_ih[tag * G4H + row]     + b_hh[tag * G4H + row];
            const float bi1 = b_ih[tag * G4H + row + 1] + b_hh[tag * G4H + row + 1];
            const float bi2 = b_ih[tag * G4H + row + 2] + b_hh[tag * G4H + row + 2];
            const float bi3 = b_ih[tag * G4H + row + 3] + b_hh[tag * G4H + row + 3];
            for (int tl = 0; tl < nc; ++tl) {
                float4 x0 = *(const float4*)&xc[tl][4 * lane];
                float4 x1 = *(const float4*)&xc[tl][256 + 4 * lane];
                float d0 = wa0.x*x0.x + wa0.y*x0.y + wa0.z*x0.z + wa0.w*x0.w
                         + wa1.x*x1.x + wa1.y*x1.y + wa1.z*x1.z + wa1.w*x1.w;
                float d1 = wb0.x*x0.x + wb0.y*x0.y + wb0.z*x0.z + wb0.w*x0.w
                         + wb1.x*x1.x + wb1.y*x1.y + wb1.z*x1.z + wb1.w*x1.w;
                float d2 = wc0.x*x0.x + wc0.y*x0.y + wc0.z*x0.z + wc0.w*x0.w
                         + wc1.x*x1.x + wc1.y*x1.y + wc1.z*x1.z + wc1.w*x1.w;
                float d3 = wd0.x*x0.x + wd0.y*x0.y + wd0.z*x0.z + wd0.w*x0.w
                         + wd1.x*x1.x + wd1.y*x1.y + wd1.z*x1.z + wd1.w*x1.w;
                #pragma unroll
                for (int m = 32; m >= 1; m >>= 1) {
                    d0 += __shfl_xor(d0, m, 64);
                    d1 += __shfl_xor(d1, m, 64);
                    d2 += __shfl_xor(d2, m, 64);
                    d3 += __shfl_xor(d3, m, 64);
                }
                if (lane == 0) {
                    float* zr = Z + (size_t)list[c0 + tl] * G4H + row;
                    zr[0] = d0 + bi0; zr[1] = d1 + bi1;
                    zr[2] = d2 + bi2; zr[3] = d3 + bi3;
                }
            }
        }
    }
}

// ---------------------------------------------------------------------------
// Kernel B: sequential LSTM. 128 co-resident blocks; block b, wave w owns
// h index j = 4b + w. Handshake: packed {f32 h, u32 step+1} relaxed agent
// atomics into hist. R5: depth-4 pipelined poll (3 samples in flight).
// R7 (this round): the explicit `s_waitcnt vmcnt(0)` between the weight
// issue and the poll is REMOVED (compiler memory barrier only). vmcnt FIFO
// semantics make it redundant: when the newest poll sample completes, all
// older weight loads are complete too, so the dot path pays nothing — but
// the FIRST poll samples now issue immediately and overlap the ~0.5 µs
// weight drain instead of serializing behind it. Re-sampling iterations
// wait only on their own samples (weights long done), so the depth-4
// pipeline is preserved (R6's mistake — samples behind an in-flight burst
// while re-sampling — is avoided because the burst completes before any
// re-sample is examined).
// No memset: 0xAA poison never matches a valid tag (1..512).
// ---------------------------------------------------------------------------
__global__ __launch_bounds__(256) void lstm_seq(
    const int* __restrict__ tag_ids,
    const float* __restrict__ h0,       // [HID]
    const float* __restrict__ c0,       // [HID]
    const float* __restrict__ W_hh,     // [NTAG, G4H, HID]
    const float* __restrict__ Z,        // [SEQ, G4H]
    const float* __restrict__ W_fc,     // [HID]
    const float* __restrict__ b_fc,     // [1]
    ull* __restrict__ hist,             // [SEQ, HID] packed {tag,f32} scratch
    float* __restrict__ d_out)          // [1 + HID + HID]
{
    __shared__ int tags[SEQ];
    __shared__ __align__(16) float hsh[2][HID];
    __shared__ float red[256];

    const int tid  = threadIdx.x;
    const int b    = blockIdx.x;
    const int wave = tid >> 6, lane = tid & 63;
    const int j    = b * 4 + wave;      // owned h index

    for (int t = tid; t < SEQ; t += 256) tags[t] = tag_ids[t];
    __syncthreads();

    float c    = (lane == 0) ? c0[j] : 0.f;
    float hval = 0.f;

    for (int t = 0; t < SEQ; ++t) {
        const int tag = tags[t];
        // ---- h-independent loads, issued BEFORE the poll ----
        const float* wbase = W_hh + (size_t)tag * G4H * HID;
        const float4* r;
        r = (const float4*)(wbase + (size_t)(j)        * HID);
        float4 wi0 = r[lane], wi1 = r[64 + lane];
        r = (const float4*)(wbase + (size_t)(512 + j)  * HID);
        float4 wf0 = r[lane], wf1 = r[64 + lane];
        r = (const float4*)(wbase + (size_t)(1024 + j) * HID);
        float4 wg0 = r[lane], wg1 = r[64 + lane];
        r = (const float4*)(wbase + (size_t)(1536 + j) * HID);
        float4 wo0 = r[lane], wo1 = r[64 + lane];

        float zi = 0.f, zf = 0.f, zg = 0.f, zo = 0.f;
        if (lane == 0) {
            const float* zt = Z + (size_t)t * G4H;
            zi = zt[j]; zf = zt[512 + j]; zg = zt[1024 + j]; zo = zt[1536 + j];
        }

        // Compiler-level pin ONLY (no hardware drain): weight loads may not
        // sink below, poll loads may not hoist above. vmcnt FIFO guarantees
        // weights complete by the time any poll sample completes, so the
        // drain overlaps the first poll samples instead of preceding them.
        asm volatile("" ::: "memory");

        // ---- obtain this thread's h pair (h[2tid], h[2tid+1]) ----
        float v0, v1;
        if (t == 0) {
            v0 = h0[2 * tid]; v1 = h0[2 * tid + 1];
        } else {
            const ull* pa = hist + (size_t)(t - 1) * HID + 2 * tid;
            const ull* pb = pa + 1;
            const unsigned want = (unsigned)t;
            // depth-4 pipelined poll: check oldest sample while 3 newer
            // samples are already in flight -> sampling period ~ latency/3.
            ull a0 = __hip_atomic_load(pa, __ATOMIC_RELAXED, __HIP_MEMORY_SCOPE_AGENT);
            ull b0 = __hip_atomic_load(pb, __ATOMIC_RELAXED, __HIP_MEMORY_SCOPE_AGENT);
            ull a1 = __hip_atomic_load(pa, __ATOMIC_RELAXED, __HIP_MEMORY_SCOPE_AGENT);
            ull b1 = __hip_atomic_load(pb, __ATOMIC_RELAXED, __HIP_MEMORY_SCOPE_AGENT);
            ull a2 = __hip_atomic_load(pa, __ATOMIC_RELAXED, __HIP_MEMORY_SCOPE_AGENT);
            ull b2 = __hip_atomic_load(pb, __ATOMIC_RELAXED, __HIP_MEMORY_SCOPE_AGENT);
            while ((unsigned)(a0 >> 32) != want || (unsigned)(b0 >> 32) != want) {
                a0 = a1; b0 = b1;
                a1 = a2; b1 = b2;
                a2 = __hip_atomic_load(pa, __ATOMIC_RELAXED, __HIP_MEMORY_SCOPE_AGENT);
                b2 = __hip_atomic_load(pb, __ATOMIC_RELAXED, __HIP_MEMORY_SCOPE_AGENT);
            }
            v0 = __uint_as_float((unsigned)a0);
            v1 = __uint_as_float((unsigned)b0);
        }
        const int hb = t & 1;
        hsh[hb][2 * tid]     = v0;
        hsh[hb][2 * tid + 1] = v1;
        __syncthreads();

        const float4 ha = *(const float4*)&hsh[hb][4 * lane];
        const float4 hc = *(const float4*)&hsh[hb][256 + 4 * lane];

        // ---- 4 dot products + butterfly reduce ----
        float di = wi0.x*ha.x + wi0.y*ha.y + wi0.z*ha.z + wi0.w*ha.w
                 + wi1.x*hc.x + wi1.y*hc.y + wi1.z*hc.z + wi1.w*hc.w;
        float df = wf0.x*ha.x + wf0.y*ha.y + wf0.z*ha.z + wf0.w*ha.w
                 + wf1.x*hc.x + wf1.y*hc.y + wf1.z*hc.z + wf1.w*hc.w;
        float dg = wg0.x*ha.x + wg0.y*ha.y + wg0.z*ha.z + wg0.w*ha.w
                 + wg1.x*hc.x + wg1.y*hc.y + wg1.z*hc.z + wg1.w*hc.w;
        float do_ = wo0.x*ha.x + wo0.y*ha.y + wo0.z*ha.z + wo0.w*ha.w
                  + wo1.x*hc.x + wo1.y*hc.y + wo1.z*hc.z + wo1.w*hc.w;
        #pragma unroll
        for (int m = 32; m >= 1; m >>= 1) {
            di  += __shfl_xor(di,  m, 64);
            df  += __shfl_xor(df,  m, 64);
            dg  += __shfl_xor(dg,  m, 64);
            do_ += __shfl_xor(do_, m, 64);
        }

        if (lane == 0) {
            float gi = zi + di, gf = zf + df, gg = zg + dg, go = zo + do_;
            float si = fast_sigmoid(gi);
            float sf = fast_sigmoid(gf);
            float so = fast_sigmoid(go);
            float tg = fast_tanh(gg);
            c = sf * c + si * tg;
            hval = so * fast_tanh(c);
            ull pk = ((ull)(unsigned)(t + 1) << 32) | (ull)__float_as_uint(hval);
            __hip_atomic_store(&hist[(size_t)t * HID + j], pk,
                               __ATOMIC_RELAXED, __HIP_MEMORY_SCOPE_AGENT);
        }
        // hsh is double-buffered; the single per-step barrier bounds skew < 2.
    }

    // ---- epilogue: h, c slices ----
    if (lane == 0) {
        d_out[1 + j]       = hval;
        d_out[1 + HID + j] = c;
    }

    // ---- block 0: out = sigmoid(h_final . W_fc + b_fc) ----
    if (b == 0) {
        const ull* hp = hist + (size_t)(SEQ - 1) * HID;
        ull a  = __hip_atomic_load(&hp[2 * tid],     __ATOMIC_RELAXED, __HIP_MEMORY_SCOPE_AGENT);
        ull bq = __hip_atomic_load(&hp[2 * tid + 1], __ATOMIC_RELAXED, __HIP_MEMORY_SCOPE_AGENT);
        while ((unsigned)(a >> 32) != (unsigned)SEQ || (unsigned)(bq >> 32) != (unsigned)SEQ) {
            a  = __hip_atomic_load(&hp[2 * tid],     __ATOMIC_RELAXED, __HIP_MEMORY_SCOPE_AGENT);
            bq = __hip_atomic_load(&hp[2 * tid + 1], __ATOMIC_RELAXED, __HIP_MEMORY_SCOPE_AGENT);
        }
        float s = __uint_as_float((unsigned)a)  * W_fc[2 * tid]
                + __uint_as_float((unsigned)bq) * W_fc[2 * tid + 1];
        red[tid] = s;
        __syncthreads();
        #pragma unroll
        for (int off = 128; off > 0; off >>= 1) {
            if (tid < off) red[tid] += red[tid + off];
            __syncthreads();
        }
        if (tid == 0)
            d_out[0] = fast_sigmoid(red[0] + b_fc[0]);
    }
}

extern "C" void kernel_launch(void* const* d_in, const int* in_sizes, int n_in,
                              void* d_out, int out_size, void* d_ws, size_t ws_size,
                              hipStream_t stream) {
    const int*   x       = (const int*)d_in[0];
    const int*   tag_ids = (const int*)d_in[1];
    const float* h0      = (const float*)d_in[2];
    const float* c0      = (const float*)d_in[3];
    const float* emb     = (const float*)d_in[4];
    const float* W_ih    = (const float*)d_in[5];
    const float* W_hh    = (const float*)d_in[6];
    const float* b_ih    = (const float*)d_in[7];
    const float* b_hh    = (const float*)d_in[8];
    const float* W_fc    = (const float*)d_in[9];
    const float* b_fc    = (const float*)d_in[10];
    float* out = (float*)d_out;

    // workspace layout: Z (4 MB) | hist (2 MB). No memset: 0xAA poison never
    // matches a valid step tag (1..512).
    const size_t zBytes = (size_t)SEQ * G4H * sizeof(float);
    float* Z    = (float*)d_ws;
    ull*   hist = (ull*)((char*)d_ws + zBytes);

    dim3 gA(NTAG, 32);
    precompute_z<<<gA, 256, 0, stream>>>(x, tag_ids, emb, W_ih, b_ih, b_hh, Z);
    lstm_seq<<<NBLK, 256, 0, stream>>>(tag_ids, h0, c0, W_hh, Z, W_fc, b_fc,
                                       hist, out);
}

// Round 5
// 1339.921 us; speedup vs baseline: 2.1127x; 1.1301x over previous
//
#include <hip/hip_runtime.h>

#define VOCAB 32000
#define EMB 512
#define HID 512
#define NTAG 36
#define SEQ 512
#define G4H 2048   // 4*HID
#define NBLK 128
#define XCHUNK 32

typedef unsigned long long ull;
// native clang vector type: required by __builtin_nontemporal_load
// (HIP float4 is a struct and is rejected by the builtin)
typedef float f4 __attribute__((ext_vector_type(4)));

__device__ __forceinline__ float fast_tanh(float x) {
    // 1 - 2/(e^{2x}+1); saturates to +-1 correctly for large |x|
    float e = __expf(2.f * x);
    return 1.f - 2.f / (e + 1.f);
}
__device__ __forceinline__ float fast_sigmoid(float x) {
    return 1.f / (1.f + __expf(-x));
}

// ---------------------------------------------------------------------------
// Kernel A: Z[t][r] = W_ih[tag_t] @ emb[x_t] + b_ih[tag_t] + b_hh[tag_t]
// grid (NTAG, 32): block = (tag, 64-row chunk). 4-row batching per wave.
// R8 (compile-fixed): W_ih read via __builtin_nontemporal_load on an
// ext_vector_type(4) pointer (nt bit -> LLC no-allocate). W_ih is
// single-use per iteration; letting it allocate in the 256 MB LLC evicted
// W_hh (144 MB) every iteration, which is why lstm_seq showed 860 MB of HBM
// fetch against a 144 MB compulsory footprint. With W_ih streaming past the
// LLC, W_hh stays LLC-resident across iterations.
// ---------------------------------------------------------------------------
__global__ __launch_bounds__(256) void precompute_z(
    const int* __restrict__ x,          // [SEQ] token ids
    const int* __restrict__ tag_ids,    // [SEQ]
    const float* __restrict__ emb,      // [VOCAB, EMB]
    const float* __restrict__ W_ih,     // [NTAG, G4H, EMB]
    const float* __restrict__ b_ih,     // [NTAG, G4H]
    const float* __restrict__ b_hh,     // [NTAG, G4H]
    float* __restrict__ Z)              // [SEQ, G4H]
{
    __shared__ int list[SEQ];
    __shared__ int cnt;
    __shared__ __align__(16) float xc[XCHUNK][EMB];   // 64 KB x-cache

    const int tid  = threadIdx.x;
    const int tag  = blockIdx.x;
    const int row0 = blockIdx.y * 64;
    const int wave = tid >> 6, lane = tid & 63;

    if (tid == 0) cnt = 0;
    __syncthreads();
    for (int t = tid; t < SEQ; t += 256)
        if (tag_ids[t] == tag) { int p = atomicAdd(&cnt, 1); list[p] = t; }
    __syncthreads();
    const int n = cnt;

    for (int c0 = 0; c0 < n; c0 += XCHUNK) {
        const int nc = min(XCHUNK, n - c0);
        __syncthreads();   // protect xc before overwrite
        for (int idx = tid; idx < nc * 128; idx += 256) {
            int tl = idx >> 7, k4 = idx & 127;
            int t = list[c0 + tl];
            ((float4*)xc[tl])[k4] = ((const float4*)(emb + (size_t)x[t] * EMB))[k4];
        }
        __syncthreads();
        for (int rr = 0; rr < 16; rr += 4) {
            const int row = row0 + wave * 16 + rr;
            const float* w0p = W_ih + ((size_t)tag * G4H + row) * EMB;
            const float* w1p = w0p + EMB;
            const float* w2p = w0p + 2 * EMB;
            const float* w3p = w0p + 3 * EMB;
            // nt loads: single-use weight stream, do not allocate in LLC
            const f4 wa0 = __builtin_nontemporal_load(&((const f4*)w0p)[lane]);
            const f4 wa1 = __builtin_nontemporal_load(&((const f4*)w0p)[64 + lane]);
            const f4 wb0 = __builtin_nontemporal_load(&((const f4*)w1p)[lane]);
            const f4 wb1 = __builtin_nontemporal_load(&((const f4*)w1p)[64 + lane]);
            const f4 wc0 = __builtin_nontemporal_load(&((const f4*)w2p)[lane]);
            const f4 wc1 = __builtin_nontemporal_load(&((const f4*)w2p)[64 + lane]);
            const f4 wd0 = __builtin_nontemporal_load(&((const f4*)w3p)[lane]);
            const f4 wd1 = __builtin_nontemporal_load(&((const f4*)w3p)[64 + lane]);
            const float bi0 = b_ih[tag * G4H + row]     + b_hh[tag * G4H + row];
            const float bi1 = b_ih[tag * G4H + row + 1] + b_hh[tag * G4H + row + 1];
            const float bi2 = b_ih[tag * G4H + row + 2] + b_hh[tag * G4H + row + 2];
            const float bi3 = b_ih[tag * G4H + row + 3] + b_hh[tag * G4H + row + 3];
            for (int tl = 0; tl < nc; ++tl) {
                float4 x0 = *(const float4*)&xc[tl][4 * lane];
                float4 x1 = *(const float4*)&xc[tl][256 + 4 * lane];
                float d0 = wa0.x*x0.x + wa0.y*x0.y + wa0.z*x0.z + wa0.w*x0.w
                         + wa1.x*x1.x + wa1.y*x1.y + wa1.z*x1.z + wa1.w*x1.w;
                float d1 = wb0.x*x0.x + wb0.y*x0.y + wb0.z*x0.z + wb0.w*x0.w
                         + wb1.x*x1.x + wb1.y*x1.y + wb1.z*x1.z + wb1.w*x1.w;
                float d2 = wc0.x*x0.x + wc0.y*x0.y + wc0.z*x0.z + wc0.w*x0.w
                         + wc1.x*x1.x + wc1.y*x1.y + wc1.z*x1.z + wc1.w*x1.w;
                float d3 = wd0.x*x0.x + wd0.y*x0.y + wd0.z*x0.z + wd0.w*x0.w
                         + wd1.x*x1.x + wd1.y*x1.y + wd1.z*x1.z + wd1.w*x1.w;
                #pragma unroll
                for (int m = 32; m >= 1; m >>= 1) {
                    d0 += __shfl_xor(d0, m, 64);
                    d1 += __shfl_xor(d1, m, 64);
                    d2 += __shfl_xor(d2, m, 64);
                    d3 += __shfl_xor(d3, m, 64);
                }
                if (lane == 0) {
                    float* zr = Z + (size_t)list[c0 + tl] * G4H + row;
                    zr[0] = d0 + bi0; zr[1] = d1 + bi1;
                    zr[2] = d2 + bi2; zr[3] = d3 + bi3;
                }
            }
        }
    }
}

// ---------------------------------------------------------------------------
// Kernel B: sequential LSTM. 128 co-resident blocks; block b, wave w owns
// h index j = 4b + w. Handshake: packed {f32 h, u32 step+1} relaxed agent
// atomics into hist. R5 structure (verified 1.9 us/step local optimum):
// weights issued, vmcnt(0) drain, THEN depth-4 pipelined poll. R6/R7
// established that removing or reordering the drain regresses (the drain
// provides intra-step phase separation + a fresh empty-queue poll pipeline).
// DO NOT touch the sync structure; this round attacks the drain's LENGTH
// via LLC residency (kernel A nt loads) instead.
// No memset: 0xAA poison never matches a valid tag (1..512).
// ---------------------------------------------------------------------------
__global__ __launch_bounds__(256) void lstm_seq(
    const int* __restrict__ tag_ids,
    const float* __restrict__ h0,       // [HID]
    const float* __restrict__ c0,       // [HID]
    const float* __restrict__ W_hh,     // [NTAG, G4H, HID]
    const float* __restrict__ Z,        // [SEQ, G4H]
    const float* __restrict__ W_fc,     // [HID]
    const float* __restrict__ b_fc,     // [1]
    ull* __restrict__ hist,             // [SEQ, HID] packed {tag,f32} scratch
    float* __restrict__ d_out)          // [1 + HID + HID]
{
    __shared__ int tags[SEQ];
    __shared__ __align__(16) float hsh[2][HID];
    __shared__ float red[256];

    const int tid  = threadIdx.x;
    const int b    = blockIdx.x;
    const int wave = tid >> 6, lane = tid & 63;
    const int j    = b * 4 + wave;      // owned h index

    for (int t = tid; t < SEQ; t += 256) tags[t] = tag_ids[t];
    __syncthreads();

    float c    = (lane == 0) ? c0[j] : 0.f;
    float hval = 0.f;

    for (int t = 0; t < SEQ; ++t) {
        const int tag = tags[t];
        // ---- h-independent loads, issued and completed before the poll ----
        const float* wbase = W_hh + (size_t)tag * G4H * HID;
        const float4* r;
        r = (const float4*)(wbase + (size_t)(j)        * HID);
        float4 wi0 = r[lane], wi1 = r[64 + lane];
        r = (const float4*)(wbase + (size_t)(512 + j)  * HID);
        float4 wf0 = r[lane], wf1 = r[64 + lane];
        r = (const float4*)(wbase + (size_t)(1024 + j) * HID);
        float4 wg0 = r[lane], wg1 = r[64 + lane];
        r = (const float4*)(wbase + (size_t)(1536 + j) * HID);
        float4 wo0 = r[lane], wo1 = r[64 + lane];

        float zi = 0.f, zf = 0.f, zg = 0.f, zo = 0.f;
        if (lane == 0) {
            const float* zt = Z + (size_t)t * G4H;
            zi = zt[j]; zf = zt[512 + j]; zg = zt[1024 + j]; zo = zt[1536 + j];
        }

        // Pin: loads above may not sink below (memory clobber) and are
        // complete here — off the post-discovery critical path.
        asm volatile("s_waitcnt vmcnt(0)" ::: "memory");

        // ---- obtain this thread's h pair (h[2tid], h[2tid+1]) ----
        float v0, v1;
        if (t == 0) {
            v0 = h0[2 * tid]; v1 = h0[2 * tid + 1];
        } else {
            const ull* pa = hist + (size_t)(t - 1) * HID + 2 * tid;
            const ull* pb = pa + 1;
            const unsigned want = (unsigned)t;
            // depth-4 pipelined poll: check oldest sample while 3 newer
            // samples are already in flight -> sampling period ~ latency/3.
            ull a0 = __hip_atomic_load(pa, __ATOMIC_RELAXED, __HIP_MEMORY_SCOPE_AGENT);
            ull b0 = __hip_atomic_load(pb, __ATOMIC_RELAXED, __HIP_MEMORY_SCOPE_AGENT);
            ull a1 = __hip_atomic_load(pa, __ATOMIC_RELAXED, __HIP_MEMORY_SCOPE_AGENT);
            ull b1 = __hip_atomic_load(pb, __ATOMIC_RELAXED, __HIP_MEMORY_SCOPE_AGENT);
            ull a2 = __hip_atomic_load(pa, __ATOMIC_RELAXED, __HIP_MEMORY_SCOPE_AGENT);
            ull b2 = __hip_atomic_load(pb, __ATOMIC_RELAXED, __HIP_MEMORY_SCOPE_AGENT);
            while ((unsigned)(a0 >> 32) != want || (unsigned)(b0 >> 32) != want) {
                a0 = a1; b0 = b1;
                a1 = a2; b1 = b2;
                a2 = __hip_atomic_load(pa, __ATOMIC_RELAXED, __HIP_MEMORY_SCOPE_AGENT);
                b2 = __hip_atomic_load(pb, __ATOMIC_RELAXED, __HIP_MEMORY_SCOPE_AGENT);
            }
            v0 = __uint_as_float((unsigned)a0);
            v1 = __uint_as_float((unsigned)b0);
        }
        const int hb = t & 1;
        hsh[hb][2 * tid]     = v0;
        hsh[hb][2 * tid + 1] = v1;
        __syncthreads();

        const float4 ha = *(const float4*)&hsh[hb][4 * lane];
        const float4 hc = *(const float4*)&hsh[hb][256 + 4 * lane];

        // ---- 4 dot products + butterfly reduce ----
        float di = wi0.x*ha.x + wi0.y*ha.y + wi0.z*ha.z + wi0.w*ha.w
                 + wi1.x*hc.x + wi1.y*hc.y + wi1.z*hc.z + wi1.w*hc.w;
        float df = wf0.x*ha.x + wf0.y*ha.y + wf0.z*ha.z + wf0.w*ha.w
                 + wf1.x*hc.x + wf1.y*hc.y + wf1.z*hc.z + wf1.w*hc.w;
        float dg = wg0.x*ha.x + wg0.y*ha.y + wg0.z*ha.z + wg0.w*ha.w
                 + wg1.x*hc.x + wg1.y*hc.y + wg1.z*hc.z + wg1.w*hc.w;
        float do_ = wo0.x*ha.x + wo0.y*ha.y + wo0.z*ha.z + wo0.w*ha.w
                  + wo1.x*hc.x + wo1.y*hc.y + wo1.z*hc.z + wo1.w*hc.w;
        #pragma unroll
        for (int m = 32; m >= 1; m >>= 1) {
            di  += __shfl_xor(di,  m, 64);
            df  += __shfl_xor(df,  m, 64);
            dg  += __shfl_xor(dg,  m, 64);
            do_ += __shfl_xor(do_, m, 64);
        }

        if (lane == 0) {
            float gi = zi + di, gf = zf + df, gg = zg + dg, go = zo + do_;
            float si = fast_sigmoid(gi);
            float sf = fast_sigmoid(gf);
            float so = fast_sigmoid(go);
            float tg = fast_tanh(gg);
            c = sf * c + si * tg;
            hval = so * fast_tanh(c);
            ull pk = ((ull)(unsigned)(t + 1) << 32) | (ull)__float_as_uint(hval);
            __hip_atomic_store(&hist[(size_t)t * HID + j], pk,
                               __ATOMIC_RELAXED, __HIP_MEMORY_SCOPE_AGENT);
        }
        // hsh is double-buffered; the single per-step barrier bounds skew < 2.
    }

    // ---- epilogue: h, c slices ----
    if (lane == 0) {
        d_out[1 + j]       = hval;
        d_out[1 + HID + j] = c;
    }

    // ---- block 0: out = sigmoid(h_final . W_fc + b_fc) ----
    if (b == 0) {
        const ull* hp = hist + (size_t)(SEQ - 1) * HID;
        ull a  = __hip_atomic_load(&hp[2 * tid],     __ATOMIC_RELAXED, __HIP_MEMORY_SCOPE_AGENT);
        ull bq = __hip_atomic_load(&hp[2 * tid + 1], __ATOMIC_RELAXED, __HIP_MEMORY_SCOPE_AGENT);
        while ((unsigned)(a >> 32) != (unsigned)SEQ || (unsigned)(bq >> 32) != (unsigned)SEQ) {
            a  = __hip_atomic_load(&hp[2 * tid],     __ATOMIC_RELAXED, __HIP_MEMORY_SCOPE_AGENT);
            bq = __hip_atomic_load(&hp[2 * tid + 1], __ATOMIC_RELAXED, __HIP_MEMORY_SCOPE_AGENT);
        }
        float s = __uint_as_float((unsigned)a)  * W_fc[2 * tid]
                + __uint_as_float((unsigned)bq) * W_fc[2 * tid + 1];
        red[tid] = s;
        __syncthreads();
        #pragma unroll
        for (int off = 128; off > 0; off >>= 1) {
            if (tid < off) red[tid] += red[tid + off];
            __syncthreads();
        }
        if (tid == 0)
            d_out[0] = fast_sigmoid(red[0] + b_fc[0]);
    }
}

extern "C" void kernel_launch(void* const* d_in, const int* in_sizes, int n_in,
                              void* d_out, int out_size, void* d_ws, size_t ws_size,
                              hipStream_t stream) {
    const int*   x       = (const int*)d_in[0];
    const int*   tag_ids = (const int*)d_in[1];
    const float* h0      = (const float*)d_in[2];
    const float* c0      = (const float*)d_in[3];
    const float* emb     = (const float*)d_in[4];
    const float* W_ih    = (const float*)d_in[5];
    const float* W_hh    = (const float*)d_in[6];
    const float* b_ih    = (const float*)d_in[7];
    const float* b_hh    = (const float*)d_in[8];
    const float* W_fc    = (const float*)d_in[9];
    const float* b_fc    = (const float*)d_in[10];
    float* out = (float*)d_out;

    // workspace layout: Z (4 MB) | hist (2 MB). No memset: 0xAA poison never
    // matches a valid step tag (1..512).
    const size_t zBytes = (size_t)SEQ * G4H * sizeof(float);
    float* Z    = (float*)d_ws;
    ull*   hist = (ull*)((char*)d_ws + zBytes);

    dim3 gA(NTAG, 32);
    precompute_z<<<gA, 256, 0, stream>>>(x, tag_ids, emb, W_ih, b_ih, b_hh, Z);
    lstm_seq<<<NBLK, 256, 0, stream>>>(tag_ids, h0, c0, W_hh, Z, W_fc, b_fc,
                                       hist, out);
}